// Round 10
// baseline (146.892 us; speedup 1.0000x reference)
//
#include <hip/hip_runtime.h>

// NeRF hierarchical sampler: 16 lanes per ray, 4 rays per wave64, 2 waves/block.
// All LDS traffic is wave-private (16-lane ray groups) -> no barriers needed.
// Cross-lane via DPP where possible (xor1/xor2/xor8, row_shr scans); xor4 = swizzle.
// Search levels 1-2 are register broadcasts (cdf[16/32/48] via shfl) -> 5 LDS steps.
// Per-ray LDS (RSTR=324 floats, 16B-aligned):
//   [0..191]   srt  : staging (coarse 64 + fine 128), later the sorted 192
//   [192..255] cdfB : cdf[1..64]  (cdf[0]=0 handled implicitly: u>=0 always)
//   [256..320] edg  : 65-entry z_edges
#define RPW 4          // rays per wave
#define RPB 8          // rays per block (2 waves * 4)
#define RSTR 324       // per-ray LDS stride (floats); 324*4B = 1296B (16B mult)

template<int CTRL, bool BC>
__device__ __forceinline__ float updpp(float old, float x) {
    return __int_as_float(__builtin_amdgcn_update_dpp(
        __float_as_int(old), __float_as_int(x), CTRL, 0xF, 0xF, BC));
}

// One bitonic substage of the 256-element network, row-major 16 elems/lane.
// e = 16*sl + h; asc(e) = ((e&K)==0); partner = e ^ J.
template<int K, int J>
__device__ __forceinline__ void substage(float (&y)[16], const int sl) {
    if constexpr (J >= 16) {                     // cross-lane: lm = J/16 in {1,2,4,8}
        constexpr int lm = J >> 4;
        const bool uasc = ((sl & (K >> 4)) == 0);          // K >= 32 here
        #pragma unroll
        for (int h = 0; h < 16; ++h) {
            float p;
            if constexpr (lm == 1)      p = updpp<0xB1, true>(0.0f, y[h]); // xor1
            else if constexpr (lm == 2) p = updpp<0x4E, true>(0.0f, y[h]); // xor2
            else if constexpr (lm == 8) p = updpp<0x128,true>(0.0f, y[h]); // xor8
            else                        p = __shfl_xor(y[h], 4);           // xor4
            const bool tmin = (((sl & lm) == 0) == uasc);
            y[h] = tmin ? fminf(y[h], p) : fmaxf(y[h], p);
        }
    } else {                                     // in-register pairs (h, h^J)
        bool dirlane = true;
        if constexpr (K == 16)      dirlane = ((sl & 1) == 0);        // e&16
        else if constexpr (K >= 32) dirlane = ((sl & (K >> 4)) == 0); // e&K
        #pragma unroll
        for (int h = 0; h < 16; ++h) {
            if ((h & J) == 0) {
                const int b = h ^ J;             // compile-time after unroll
                bool dr;
                if constexpr (K <= 8) dr = ((h & K) == 0);
                else                  dr = dirlane;
                float lo_ = fminf(y[h], y[b]);
                float hi_ = fmaxf(y[h], y[b]);
                y[h] = dr ? lo_ : hi_;
                y[b] = dr ? hi_ : lo_;
            }
        }
    }
}

__global__ __launch_bounds__(128) void hier_sampler(
    const float* __restrict__ org, const float* __restrict__ dir,
    const float* __restrict__ dens, const float* __restrict__ trand,
    const float* __restrict__ uu, float* __restrict__ out_pts,
    float* __restrict__ out_z)
{
    const int tid  = threadIdx.x;
    const int sl   = tid & 15;                 // sub-lane within ray group
    const int rloc = tid >> 4;                 // local ray id in block, 0..7
    const int ray  = blockIdx.x * RPB + rloc;

    __shared__ __align__(16) float lds[RPB * RSTR];
    float* srt  = &lds[rloc * RSTR];
    float* cdfB = srt + 192;
    float* edg  = srt + 256;

    // ---- coarse stratified sampling: 4 samples/lane, j = 4*sl+m ----
    const float step = 4.0f / 63.0f;
    const float4 t4 = ((const float4*)trand)[(size_t)ray * 16 + sl];
    const float4 d4 = ((const float4*)dens )[(size_t)ray * 16 + sl];
    const float tarr[4] = {t4.x, t4.y, t4.z, t4.w};
    const float darr[4] = {d4.x, d4.y, d4.z, d4.w};
    float zv[4];
    #pragma unroll
    for (int m = 0; m < 4; ++m) {
        int j = 4*sl + m;
        float zg = 2.0f + step * (float)j;
        float lo = (j == 0)  ? 2.0f : (zg - 0.5f*step);   // mids are zg +- step/2
        float up = (j == 63) ? 6.0f : (zg + 0.5f*step);
        zv[m] = lo + (up - lo) * tarr[m];
    }
    float znext0 = updpp<0x101,true>(0.0f, zv[0]);        // shfl_down 1 (sl15 masked)
    float delta[4] = { zv[1]-zv[0], zv[2]-zv[1], zv[3]-zv[2],
                       (sl == 15) ? 1e10f : (znext0 - zv[3]) };

    // ---- transmittance weights (in-lane 4 + cross-lane 16 scans) ----
    float a[4], pp[4];
    {
        float run = 1.0f;
        #pragma unroll
        for (int m = 0; m < 4; ++m) {
            a[m] = 1.0f - __expf(-darr[m] * delta[m]);
            run *= (1.0f - a[m] + 1e-10f);
            pp[m] = run;                        // in-lane inclusive product
        }
    }
    // Hillis-Steele inclusive product scan over 16 lanes, identity=1.0
    float P = pp[3];
    P *= updpp<0x111,false>(1.0f, P);
    P *= updpp<0x112,false>(1.0f, P);
    P *= updpp<0x114,false>(1.0f, P);
    P *= updpp<0x118,false>(1.0f, P);
    float E = updpp<0x111,false>(1.0f, P);      // exclusive; sl==0 -> 1.0

    float sw[4];
    {
        float acc = 0.0f;
        #pragma unroll
        for (int m = 0; m < 4; ++m) {
            float T = (m == 0) ? E : E * pp[m-1];   // exclusive cumprod at j
            acc += a[m]*T + 1e-5f;                  // w + 1e-5, in-lane cumsum
            sw[m] = acc;
        }
    }
    // inclusive sum scan over 16 lanes, identity=0.0
    float S = sw[3];
    S += updpp<0x111,false>(0.0f, S);
    S += updpp<0x112,false>(0.0f, S);
    S += updpp<0x114,false>(0.0f, S);
    S += updpp<0x118,false>(0.0f, S);
    float Es  = updpp<0x111,false>(0.0f, S);    // exclusive; sl==0 -> 0
    float tot = __shfl(S, 15, 16);
    float itot = 1.0f / tot;

    *(float4*)(cdfB + 4*sl) = make_float4((Es+sw[0])*itot, (Es+sw[1])*itot,
                                          (Es+sw[2])*itot, (Es+sw[3])*itot);
    // register copies of cdfB[16], cdfB[32], cdfB[48] for search levels 0-1
    float bb  = Es + sw[0];
    float c16 = __shfl(bb, 4, 16)  * itot;      // cdfB[16]
    float c32 = __shfl(bb, 8, 16)  * itot;      // cdfB[32]
    float c48 = __shfl(bb, 12, 16) * itot;      // cdfB[48]

    // ---- z_edges ----
    float zp3 = updpp<0x111,true>(0.0f, zv[3]); // shfl_up 1 (sl0 masked)
    float ej0 = (sl == 0) ? (1.5f*zv[0] - 0.5f*zv[1]) : 0.5f*(zp3 + zv[0]);
    *(float4*)(edg + 4*sl) = make_float4(ej0, 0.5f*(zv[0]+zv[1]),
                                         0.5f*(zv[1]+zv[2]), 0.5f*(zv[2]+zv[3]));
    if (sl == 15) edg[64] = 1.5f*zv[3] - 0.5f*zv[2];
    // ---- stage coarse for sort ----
    *(float4*)(srt + 4*sl) = make_float4(zv[0], zv[1], zv[2], zv[3]);

    // ---- inverse-CDF fine sampling: 8 u's per lane ----
    // searchsorted(cdf65, u, 'right') = 1 + searchsorted_right(cdfB, u) since
    // cdf[0]=0 <= u always. lo in [0,64] after 7 steps; first 2 from registers.
    const float4 ua = ((const float4*)uu)[(size_t)ray*32 + 2*sl];
    const float4 ub = ((const float4*)uu)[(size_t)ray*32 + 2*sl + 1];
    const float uarr[8] = {ua.x,ua.y,ua.z,ua.w, ub.x,ub.y,ub.z,ub.w};
    float fz[8];
    #pragma unroll
    for (int t = 0; t < 8; ++t) {
        float u = uarr[t];
        // level 0: m=32 -> cdfB[32]; level 1: m=48 or 16 -> registers
        bool d0 = (c32 <= u);
        int  lo = d0 ? 33 : 0;
        int  hi = d0 ? 64 : 32;
        float cm1 = d0 ? c48 : c16;
        int  m1 = (lo + hi) >> 1;               // 48 or 16
        bool d1 = (cm1 <= u);
        lo = d1 ? m1 + 1 : lo;
        hi = d1 ? hi : m1;
        #pragma unroll
        for (int it = 0; it < 5; ++it) {
            int m = (lo + hi) >> 1;
            bool c = cdfB[m] <= u;
            lo = c ? m+1 : lo;
            hi = c ? hi  : m;
        }
        int below = lo;                          // = clip(inds-1) in [0,64]
        int above = (lo < 64) ? lo + 1 : 64;     // = clip(inds)   in [1,64]
        int bm1   = (below > 0) ? below - 1 : 0;
        float c0 = cdfB[bm1];
        if (below == 0) c0 = 0.0f;               // cdf[0] = 0
        float c1 = cdfB[above - 1];
        float e0 = edg[below], e1 = edg[above];
        float dn = c1 - c0;
        if (dn < 1e-5f) dn = 1.0f;
        float tt = (u - c0) / dn;
        fz[t] = e0 + tt * (e1 - e0);
    }
    *(float4*)(srt + 64 + 8*sl)     = make_float4(fz[0],fz[1],fz[2],fz[3]);
    *(float4*)(srt + 64 + 8*sl + 4) = make_float4(fz[4],fz[5],fz[6],fz[7]);

    // ---- load sort layout: y[h] = element 16*sl + h (pads 192..255 = 1e30) ----
    float y[16];
    if (sl < 12) {
        #pragma unroll
        for (int tq = 0; tq < 4; ++tq) {
            float4 v = *(const float4*)(srt + 16*sl + 4*tq);
            y[4*tq+0]=v.x; y[4*tq+1]=v.y; y[4*tq+2]=v.z; y[4*tq+3]=v.w;
        }
    } else {
        #pragma unroll
        for (int h = 0; h < 16; ++h) y[h] = 1.0e30f;
    }

    // ---- bitonic sort of 256: all 36 substages with compile-time (K,J) ----
    substage<2,1>(y, sl);

    substage<4,2>(y, sl);   substage<4,1>(y, sl);

    substage<8,4>(y, sl);   substage<8,2>(y, sl);   substage<8,1>(y, sl);

    substage<16,8>(y, sl);  substage<16,4>(y, sl);  substage<16,2>(y, sl);
    substage<16,1>(y, sl);

    substage<32,16>(y, sl); substage<32,8>(y, sl);  substage<32,4>(y, sl);
    substage<32,2>(y, sl);  substage<32,1>(y, sl);

    substage<64,32>(y, sl); substage<64,16>(y, sl); substage<64,8>(y, sl);
    substage<64,4>(y, sl);  substage<64,2>(y, sl);  substage<64,1>(y, sl);

    substage<128,64>(y, sl); substage<128,32>(y, sl); substage<128,16>(y, sl);
    substage<128,8>(y, sl);  substage<128,4>(y, sl);  substage<128,2>(y, sl);
    substage<128,1>(y, sl);

    substage<256,128>(y, sl); substage<256,64>(y, sl); substage<256,32>(y, sl);
    substage<256,16>(y, sl);  substage<256,8>(y, sl);  substage<256,4>(y, sl);
    substage<256,2>(y, sl);   substage<256,1>(y, sl);

    // ---- write sorted to LDS; emit sorted z straight from registers ----
    if (sl < 12) {
        size_t zb = (size_t)ray * 192 + 16*sl;
        #pragma unroll
        for (int tq = 0; tq < 4; ++tq) {
            float4 v = make_float4(y[4*tq],y[4*tq+1],y[4*tq+2],y[4*tq+3]);
            *(float4*)(srt + 16*sl + 4*tq) = v;
            *(float4*)(out_z + zb + 4*tq)  = v;
        }
    }

    // ---- emit points: per-ray group, 144 float4 chunks = 9 iterations ----
    float ox = org[(size_t)ray*3+0], oy = org[(size_t)ray*3+1], oz = org[(size_t)ray*3+2];
    float dx = dir[(size_t)ray*3+0], dy = dir[(size_t)ray*3+1], dz = dir[(size_t)ray*3+2];
    float* pbase = out_pts + (size_t)ray * 576;
    #pragma unroll
    for (int it = 0; it < 9; ++it) {
        int i  = it*16 + sl;                // chunk id 0..143, covers idx 4i..4i+3
        int q  = i / 3;
        int c0 = i - 3*q;                   // idx%3
        int k0 = i + q;                     // idx/3
        const float* zp = srt + k0;         // paired reads -> ds_read2_b32
        float z0 = zp[0];
        float z1 = zp[1];
        // m=0: ch=c0,z0    m=3: ch=c0,z1
        float o0  = (c0==0)?ox:((c0==1)?oy:oz);
        float dd0 = (c0==0)?dx:((c0==1)?dy:dz);
        float v0 = fmaf(dd0, z0, o0);
        float v3 = fmaf(dd0, z1, o0);
        // m=1: cm=c0+1 (wraps at 3 -> z1)
        int   c1i = (c0==2)?0:(c0+1);
        float zz1 = (c0==2)?z1:z0;
        float o1  = (c1i==0)?ox:((c1i==1)?oy:oz);
        float dd1 = (c1i==0)?dx:((c1i==1)?dy:dz);
        float v1 = fmaf(dd1, zz1, o1);
        // m=2: cm=c0+2 (wraps for c0>=1 -> z1)
        int   c2i = (c0==0)?2:(c0-1);
        float zz2 = (c0==0)?z0:z1;
        float o2  = (c2i==0)?ox:((c2i==1)?oy:oz);
        float dd2 = (c2i==0)?dx:((c2i==1)?dy:dz);
        float v2 = fmaf(dd2, zz2, o2);
        *(float4*)(pbase + 4*i) = make_float4(v0, v1, v2, v3);
    }
}

extern "C" void kernel_launch(void* const* d_in, const int* in_sizes, int n_in,
                              void* d_out, int out_size, void* d_ws, size_t ws_size,
                              hipStream_t stream) {
    const float* org   = (const float*)d_in[0];
    const float* dir   = (const float*)d_in[1];
    const float* dens  = (const float*)d_in[2];
    const float* trand = (const float*)d_in[3];
    const float* uv    = (const float*)d_in[4];
    int B = in_sizes[0] / 3;   // 131072

    float* out_pts = (float*)d_out;
    float* out_z   = out_pts + (size_t)B * 576;

    dim3 grid(B / RPB), block(128);
    hipLaunchKernelGGL(hier_sampler, grid, block, 0, stream,
                       org, dir, dens, trand, uv, out_pts, out_z);
}

// Round 11
// 140.507 us; speedup vs baseline: 1.0454x; 1.0454x over previous
//
#include <hip/hip_runtime.h>

// NeRF hierarchical sampler: 16 lanes per ray, 4 rays per wave64, 2 waves/block.
// All LDS traffic is wave-private (16-lane ray groups) -> no barriers needed.
// Cross-lane via DPP where possible (xor1/xor2/xor8, row_shr scans); xor4 = swizzle.
// Search levels 1-2 are register broadcasts (cdf[16/32/48] via shfl) -> 5 LDS steps.
// Outputs via nontemporal stores (write-once data; avoids L2/L3 write-allocate
// pollution -- removing NT cost ~7us in R10).
// Per-ray LDS (RSTR=324 floats, 16B-aligned):
//   [0..191]   srt  : staging (coarse 64 + fine 128), later the sorted 192
//   [192..255] cdfB : cdf[1..64]  (cdf[0]=0 handled implicitly: u>=0 always)
//   [256..320] edg  : 65-entry z_edges
#define RPW 4          // rays per wave
#define RPB 8          // rays per block (2 waves * 4)
#define RSTR 324       // per-ray LDS stride (floats); 324*4B = 1296B (16B mult)

typedef float vf4 __attribute__((ext_vector_type(4)));

template<int CTRL, bool BC>
__device__ __forceinline__ float updpp(float old, float x) {
    return __int_as_float(__builtin_amdgcn_update_dpp(
        __float_as_int(old), __float_as_int(x), CTRL, 0xF, 0xF, BC));
}

// One bitonic substage of the 256-element network, row-major 16 elems/lane.
// e = 16*sl + h; asc(e) = ((e&K)==0); partner = e ^ J.
template<int K, int J>
__device__ __forceinline__ void substage(float (&y)[16], const int sl) {
    if constexpr (J >= 16) {                     // cross-lane: lm = J/16 in {1,2,4,8}
        constexpr int lm = J >> 4;
        const bool uasc = ((sl & (K >> 4)) == 0);          // K >= 32 here
        #pragma unroll
        for (int h = 0; h < 16; ++h) {
            float p;
            if constexpr (lm == 1)      p = updpp<0xB1, true>(0.0f, y[h]); // xor1
            else if constexpr (lm == 2) p = updpp<0x4E, true>(0.0f, y[h]); // xor2
            else if constexpr (lm == 8) p = updpp<0x128,true>(0.0f, y[h]); // xor8
            else                        p = __shfl_xor(y[h], 4);           // xor4
            const bool tmin = (((sl & lm) == 0) == uasc);
            y[h] = tmin ? fminf(y[h], p) : fmaxf(y[h], p);
        }
    } else {                                     // in-register pairs (h, h^J)
        bool dirlane = true;
        if constexpr (K == 16)      dirlane = ((sl & 1) == 0);        // e&16
        else if constexpr (K >= 32) dirlane = ((sl & (K >> 4)) == 0); // e&K
        #pragma unroll
        for (int h = 0; h < 16; ++h) {
            if ((h & J) == 0) {
                const int b = h ^ J;             // compile-time after unroll
                bool dr;
                if constexpr (K <= 8) dr = ((h & K) == 0);
                else                  dr = dirlane;
                float lo_ = fminf(y[h], y[b]);
                float hi_ = fmaxf(y[h], y[b]);
                y[h] = dr ? lo_ : hi_;
                y[b] = dr ? hi_ : lo_;
            }
        }
    }
}

__global__ __launch_bounds__(128) void hier_sampler(
    const float* __restrict__ org, const float* __restrict__ dir,
    const float* __restrict__ dens, const float* __restrict__ trand,
    const float* __restrict__ uu, float* __restrict__ out_pts,
    float* __restrict__ out_z)
{
    const int tid  = threadIdx.x;
    const int sl   = tid & 15;                 // sub-lane within ray group
    const int rloc = tid >> 4;                 // local ray id in block, 0..7
    const int ray  = blockIdx.x * RPB + rloc;

    __shared__ __align__(16) float lds[RPB * RSTR];
    float* srt  = &lds[rloc * RSTR];
    float* cdfB = srt + 192;
    float* edg  = srt + 256;

    // ---- coarse stratified sampling: 4 samples/lane, j = 4*sl+m ----
    const float step = 4.0f / 63.0f;
    const float4 t4 = ((const float4*)trand)[(size_t)ray * 16 + sl];
    const float4 d4 = ((const float4*)dens )[(size_t)ray * 16 + sl];
    const float tarr[4] = {t4.x, t4.y, t4.z, t4.w};
    const float darr[4] = {d4.x, d4.y, d4.z, d4.w};
    float zv[4];
    #pragma unroll
    for (int m = 0; m < 4; ++m) {
        int j = 4*sl + m;
        float zg = 2.0f + step * (float)j;
        float lo = (j == 0)  ? 2.0f : (zg - 0.5f*step);   // mids are zg +- step/2
        float up = (j == 63) ? 6.0f : (zg + 0.5f*step);
        zv[m] = lo + (up - lo) * tarr[m];
    }
    float znext0 = updpp<0x101,true>(0.0f, zv[0]);        // shfl_down 1 (sl15 masked)
    float delta[4] = { zv[1]-zv[0], zv[2]-zv[1], zv[3]-zv[2],
                       (sl == 15) ? 1e10f : (znext0 - zv[3]) };

    // ---- transmittance weights (in-lane 4 + cross-lane 16 scans) ----
    float a[4], pp[4];
    {
        float run = 1.0f;
        #pragma unroll
        for (int m = 0; m < 4; ++m) {
            a[m] = 1.0f - __expf(-darr[m] * delta[m]);
            run *= (1.0f - a[m] + 1e-10f);
            pp[m] = run;                        // in-lane inclusive product
        }
    }
    // Hillis-Steele inclusive product scan over 16 lanes, identity=1.0
    float P = pp[3];
    P *= updpp<0x111,false>(1.0f, P);
    P *= updpp<0x112,false>(1.0f, P);
    P *= updpp<0x114,false>(1.0f, P);
    P *= updpp<0x118,false>(1.0f, P);
    float E = updpp<0x111,false>(1.0f, P);      // exclusive; sl==0 -> 1.0

    float sw[4];
    {
        float acc = 0.0f;
        #pragma unroll
        for (int m = 0; m < 4; ++m) {
            float T = (m == 0) ? E : E * pp[m-1];   // exclusive cumprod at j
            acc += a[m]*T + 1e-5f;                  // w + 1e-5, in-lane cumsum
            sw[m] = acc;
        }
    }
    // inclusive sum scan over 16 lanes, identity=0.0
    float S = sw[3];
    S += updpp<0x111,false>(0.0f, S);
    S += updpp<0x112,false>(0.0f, S);
    S += updpp<0x114,false>(0.0f, S);
    S += updpp<0x118,false>(0.0f, S);
    float Es  = updpp<0x111,false>(0.0f, S);    // exclusive; sl==0 -> 0
    float tot = __shfl(S, 15, 16);
    float itot = 1.0f / tot;

    *(float4*)(cdfB + 4*sl) = make_float4((Es+sw[0])*itot, (Es+sw[1])*itot,
                                          (Es+sw[2])*itot, (Es+sw[3])*itot);
    // register copies of cdfB[16], cdfB[32], cdfB[48] for search levels 0-1
    float bb  = Es + sw[0];
    float c16 = __shfl(bb, 4, 16)  * itot;      // cdfB[16]
    float c32 = __shfl(bb, 8, 16)  * itot;      // cdfB[32]
    float c48 = __shfl(bb, 12, 16) * itot;      // cdfB[48]

    // ---- z_edges ----
    float zp3 = updpp<0x111,true>(0.0f, zv[3]); // shfl_up 1 (sl0 masked)
    float ej0 = (sl == 0) ? (1.5f*zv[0] - 0.5f*zv[1]) : 0.5f*(zp3 + zv[0]);
    *(float4*)(edg + 4*sl) = make_float4(ej0, 0.5f*(zv[0]+zv[1]),
                                         0.5f*(zv[1]+zv[2]), 0.5f*(zv[2]+zv[3]));
    if (sl == 15) edg[64] = 1.5f*zv[3] - 0.5f*zv[2];
    // ---- stage coarse for sort ----
    *(float4*)(srt + 4*sl) = make_float4(zv[0], zv[1], zv[2], zv[3]);

    // ---- inverse-CDF fine sampling: 8 u's per lane ----
    // searchsorted(cdf65, u, 'right') = 1 + searchsorted_right(cdfB, u) since
    // cdf[0]=0 <= u always. lo in [0,64] after 7 steps; first 2 from registers.
    const float4 ua = ((const float4*)uu)[(size_t)ray*32 + 2*sl];
    const float4 ub = ((const float4*)uu)[(size_t)ray*32 + 2*sl + 1];
    const float uarr[8] = {ua.x,ua.y,ua.z,ua.w, ub.x,ub.y,ub.z,ub.w};
    float fz[8];
    #pragma unroll
    for (int t = 0; t < 8; ++t) {
        float u = uarr[t];
        // level 0: m=32 -> c32; level 1: m=48 or 16 -> registers
        bool d0 = (c32 <= u);
        int  lo = d0 ? 33 : 0;
        int  hi = d0 ? 64 : 32;
        float cm1 = d0 ? c48 : c16;
        int  m1 = (lo + hi) >> 1;               // 48 or 16
        bool d1 = (cm1 <= u);
        lo = d1 ? m1 + 1 : lo;
        hi = d1 ? hi : m1;
        #pragma unroll
        for (int it = 0; it < 5; ++it) {
            int m = (lo + hi) >> 1;
            bool c = cdfB[m] <= u;
            lo = c ? m+1 : lo;
            hi = c ? hi  : m;
        }
        int below = lo;                          // = clip(inds-1) in [0,64]
        int above = (lo < 64) ? lo + 1 : 64;     // = clip(inds)   in [1,64]
        int bm1   = (below > 0) ? below - 1 : 0;
        float c0 = cdfB[bm1];
        if (below == 0) c0 = 0.0f;               // cdf[0] = 0
        float c1 = cdfB[above - 1];
        float e0 = edg[below], e1 = edg[above];
        float dn = c1 - c0;
        if (dn < 1e-5f) dn = 1.0f;
        float tt = (u - c0) / dn;
        fz[t] = e0 + tt * (e1 - e0);
    }
    *(float4*)(srt + 64 + 8*sl)     = make_float4(fz[0],fz[1],fz[2],fz[3]);
    *(float4*)(srt + 64 + 8*sl + 4) = make_float4(fz[4],fz[5],fz[6],fz[7]);

    // ---- load sort layout: y[h] = element 16*sl + h (pads 192..255 = 1e30) ----
    float y[16];
    if (sl < 12) {
        #pragma unroll
        for (int tq = 0; tq < 4; ++tq) {
            float4 v = *(const float4*)(srt + 16*sl + 4*tq);
            y[4*tq+0]=v.x; y[4*tq+1]=v.y; y[4*tq+2]=v.z; y[4*tq+3]=v.w;
        }
    } else {
        #pragma unroll
        for (int h = 0; h < 16; ++h) y[h] = 1.0e30f;
    }

    // ---- bitonic sort of 256: all 36 substages with compile-time (K,J) ----
    substage<2,1>(y, sl);

    substage<4,2>(y, sl);   substage<4,1>(y, sl);

    substage<8,4>(y, sl);   substage<8,2>(y, sl);   substage<8,1>(y, sl);

    substage<16,8>(y, sl);  substage<16,4>(y, sl);  substage<16,2>(y, sl);
    substage<16,1>(y, sl);

    substage<32,16>(y, sl); substage<32,8>(y, sl);  substage<32,4>(y, sl);
    substage<32,2>(y, sl);  substage<32,1>(y, sl);

    substage<64,32>(y, sl); substage<64,16>(y, sl); substage<64,8>(y, sl);
    substage<64,4>(y, sl);  substage<64,2>(y, sl);  substage<64,1>(y, sl);

    substage<128,64>(y, sl); substage<128,32>(y, sl); substage<128,16>(y, sl);
    substage<128,8>(y, sl);  substage<128,4>(y, sl);  substage<128,2>(y, sl);
    substage<128,1>(y, sl);

    substage<256,128>(y, sl); substage<256,64>(y, sl); substage<256,32>(y, sl);
    substage<256,16>(y, sl);  substage<256,8>(y, sl);  substage<256,4>(y, sl);
    substage<256,2>(y, sl);   substage<256,1>(y, sl);

    // ---- write sorted to LDS; emit sorted z straight from registers (NT) ----
    if (sl < 12) {
        size_t zb = (size_t)ray * 192 + 16*sl;
        #pragma unroll
        for (int tq = 0; tq < 4; ++tq) {
            *(float4*)(srt + 16*sl + 4*tq) =
                make_float4(y[4*tq],y[4*tq+1],y[4*tq+2],y[4*tq+3]);
            vf4 v = {y[4*tq], y[4*tq+1], y[4*tq+2], y[4*tq+3]};
            __builtin_nontemporal_store(v, (vf4*)(out_z + zb + 4*tq));
        }
    }

    // ---- emit points: per-ray group, 144 float4 chunks = 9 iterations ----
    float ox = org[(size_t)ray*3+0], oy = org[(size_t)ray*3+1], oz = org[(size_t)ray*3+2];
    float dx = dir[(size_t)ray*3+0], dy = dir[(size_t)ray*3+1], dz = dir[(size_t)ray*3+2];
    float* pbase = out_pts + (size_t)ray * 576;
    #pragma unroll
    for (int it = 0; it < 9; ++it) {
        int i  = it*16 + sl;                // chunk id 0..143, covers idx 4i..4i+3
        int q  = i / 3;
        int c0 = i - 3*q;                   // idx%3
        int k0 = i + q;                     // idx/3
        const float* zp = srt + k0;         // paired reads -> ds_read2_b32
        float z0 = zp[0];
        float z1 = zp[1];
        // m=0: ch=c0,z0    m=3: ch=c0,z1
        float o0  = (c0==0)?ox:((c0==1)?oy:oz);
        float dd0 = (c0==0)?dx:((c0==1)?dy:dz);
        float v0 = fmaf(dd0, z0, o0);
        float v3 = fmaf(dd0, z1, o0);
        // m=1: cm=c0+1 (wraps at 3 -> z1)
        int   c1i = (c0==2)?0:(c0+1);
        float zz1 = (c0==2)?z1:z0;
        float o1  = (c1i==0)?ox:((c1i==1)?oy:oz);
        float dd1 = (c1i==0)?dx:((c1i==1)?dy:dz);
        float v1 = fmaf(dd1, zz1, o1);
        // m=2: cm=c0+2 (wraps for c0>=1 -> z1)
        int   c2i = (c0==0)?2:(c0-1);
        float zz2 = (c0==0)?z0:z1;
        float o2  = (c2i==0)?ox:((c2i==1)?oy:oz);
        float dd2 = (c2i==0)?dx:((c2i==1)?dy:dz);
        float v2 = fmaf(dd2, zz2, o2);
        vf4 v = {v0, v1, v2, v3};
        __builtin_nontemporal_store(v, (vf4*)(pbase + 4*i));
    }
}

extern "C" void kernel_launch(void* const* d_in, const int* in_sizes, int n_in,
                              void* d_out, int out_size, void* d_ws, size_t ws_size,
                              hipStream_t stream) {
    const float* org   = (const float*)d_in[0];
    const float* dir   = (const float*)d_in[1];
    const float* dens  = (const float*)d_in[2];
    const float* trand = (const float*)d_in[3];
    const float* uv    = (const float*)d_in[4];
    int B = in_sizes[0] / 3;   // 131072

    float* out_pts = (float*)d_out;
    float* out_z   = out_pts + (size_t)B * 576;

    dim3 grid(B / RPB), block(128);
    hipLaunchKernelGGL(hier_sampler, grid, block, 0, stream,
                       org, dir, dens, trand, uv, out_pts, out_z);
}

// Round 13
// 135.993 us; speedup vs baseline: 1.0801x; 1.0332x over previous
//
#include <hip/hip_runtime.h>

// NeRF hierarchical sampler: 16 lanes per ray, 4 rays per wave64, 2 waves/block.
// All LDS traffic is wave-private (16-lane ray groups) -> no barriers needed.
// Cross-lane via DPP where possible (xor1/xor2/xor8, row_shr scans); xor4 = swizzle.
// Search levels 1-2 are register broadcasts (cdf[16/32/48] via shfl).
// Outputs via nontemporal stores; z emit goes through LDS so every NT store
// instruction is wave-contiguous (R11's register-direct z stores were 64B-strided
// per lane -> ~100MB write amplification, WRITE_SIZE 503MB vs 403MB output).
// Per-ray LDS (RSTR=324 floats, 16B-aligned):
//   [0..191]   srt  : staging (coarse 64 + fine 128), later the sorted 192
//   [192..255] cdfB : cdf[1..64]  (cdf[0]=0 handled implicitly: u>=0 always)
//   [256..320] edg  : 65-entry z_edges
#define RPW 4          // rays per wave
#define RPB 8          // rays per block (2 waves * 4)
#define RSTR 324       // per-ray LDS stride (floats); 324*4B = 1296B (16B mult)

typedef float vf4 __attribute__((ext_vector_type(4)));

template<int CTRL, bool BC>
__device__ __forceinline__ float updpp(float old, float x) {
    return __int_as_float(__builtin_amdgcn_update_dpp(
        __float_as_int(old), __float_as_int(x), CTRL, 0xF, 0xF, BC));
}

// One bitonic substage of the 256-element network, row-major 16 elems/lane.
// e = 16*sl + h; asc(e) = ((e&K)==0); partner = e ^ J.
template<int K, int J>
__device__ __forceinline__ void substage(float (&y)[16], const int sl) {
    if constexpr (J >= 16) {                     // cross-lane: lm = J/16 in {1,2,4,8}
        constexpr int lm = J >> 4;
        const bool uasc = ((sl & (K >> 4)) == 0);          // K >= 32 here
        #pragma unroll
        for (int h = 0; h < 16; ++h) {
            float p;
            if constexpr (lm == 1)      p = updpp<0xB1, true>(0.0f, y[h]); // xor1
            else if constexpr (lm == 2) p = updpp<0x4E, true>(0.0f, y[h]); // xor2
            else if constexpr (lm == 8) p = updpp<0x128,true>(0.0f, y[h]); // xor8
            else                        p = __shfl_xor(y[h], 4);           // xor4
            const bool tmin = (((sl & lm) == 0) == uasc);
            y[h] = tmin ? fminf(y[h], p) : fmaxf(y[h], p);
        }
    } else {                                     // in-register pairs (h, h^J)
        bool dirlane = true;
        if constexpr (K == 16)      dirlane = ((sl & 1) == 0);        // e&16
        else if constexpr (K >= 32) dirlane = ((sl & (K >> 4)) == 0); // e&K
        #pragma unroll
        for (int h = 0; h < 16; ++h) {
            if ((h & J) == 0) {
                const int b = h ^ J;             // compile-time after unroll
                bool dr;
                if constexpr (K <= 8) dr = ((h & K) == 0);
                else                  dr = dirlane;
                float lo_ = fminf(y[h], y[b]);
                float hi_ = fmaxf(y[h], y[b]);
                y[h] = dr ? lo_ : hi_;
                y[b] = dr ? hi_ : lo_;
            }
        }
    }
}

__global__ __launch_bounds__(128) void hier_sampler(
    const float* __restrict__ org, const float* __restrict__ dir,
    const float* __restrict__ dens, const float* __restrict__ trand,
    const float* __restrict__ uu, float* __restrict__ out_pts,
    float* __restrict__ out_z)
{
    const int tid  = threadIdx.x;
    const int sl   = tid & 15;                 // sub-lane within ray group
    const int rloc = tid >> 4;                 // local ray id in block, 0..7
    const int ray  = blockIdx.x * RPB + rloc;

    __shared__ __align__(16) float lds[RPB * RSTR];
    float* srt  = &lds[rloc * RSTR];
    float* cdfB = srt + 192;
    float* edg  = srt + 256;

    // ---- coarse stratified sampling: 4 samples/lane, j = 4*sl+m ----
    const float step = 4.0f / 63.0f;
    const float4 t4 = ((const float4*)trand)[(size_t)ray * 16 + sl];
    const float4 d4 = ((const float4*)dens )[(size_t)ray * 16 + sl];
    const float tarr[4] = {t4.x, t4.y, t4.z, t4.w};
    const float darr[4] = {d4.x, d4.y, d4.z, d4.w};
    float zv[4];
    #pragma unroll
    for (int m = 0; m < 4; ++m) {
        int j = 4*sl + m;
        float zg = 2.0f + step * (float)j;
        float lo = (j == 0)  ? 2.0f : (zg - 0.5f*step);   // mids are zg +- step/2
        float up = (j == 63) ? 6.0f : (zg + 0.5f*step);
        zv[m] = lo + (up - lo) * tarr[m];
    }
    float znext0 = updpp<0x101,true>(0.0f, zv[0]);        // shfl_down 1 (sl15 masked)
    float delta[4] = { zv[1]-zv[0], zv[2]-zv[1], zv[3]-zv[2],
                       (sl == 15) ? 1e10f : (znext0 - zv[3]) };

    // ---- transmittance weights (in-lane 4 + cross-lane 16 scans) ----
    float a[4], pp[4];
    {
        float run = 1.0f;
        #pragma unroll
        for (int m = 0; m < 4; ++m) {
            a[m] = 1.0f - __expf(-darr[m] * delta[m]);
            run *= (1.0f - a[m] + 1e-10f);
            pp[m] = run;                        // in-lane inclusive product
        }
    }
    // Hillis-Steele inclusive product scan over 16 lanes, identity=1.0
    float P = pp[3];
    P *= updpp<0x111,false>(1.0f, P);
    P *= updpp<0x112,false>(1.0f, P);
    P *= updpp<0x114,false>(1.0f, P);
    P *= updpp<0x118,false>(1.0f, P);
    float E = updpp<0x111,false>(1.0f, P);      // exclusive; sl==0 -> 1.0

    float sw[4];
    {
        float acc = 0.0f;
        #pragma unroll
        for (int m = 0; m < 4; ++m) {
            float T = (m == 0) ? E : E * pp[m-1];   // exclusive cumprod at j
            acc += a[m]*T + 1e-5f;                  // w + 1e-5, in-lane cumsum
            sw[m] = acc;
        }
    }
    // inclusive sum scan over 16 lanes, identity=0.0
    float S = sw[3];
    S += updpp<0x111,false>(0.0f, S);
    S += updpp<0x112,false>(0.0f, S);
    S += updpp<0x114,false>(0.0f, S);
    S += updpp<0x118,false>(0.0f, S);
    float Es  = updpp<0x111,false>(0.0f, S);    // exclusive; sl==0 -> 0
    float tot = __shfl(S, 15, 16);
    float itot = 1.0f / tot;

    *(float4*)(cdfB + 4*sl) = make_float4((Es+sw[0])*itot, (Es+sw[1])*itot,
                                          (Es+sw[2])*itot, (Es+sw[3])*itot);
    // register copies of cdfB[16], cdfB[32], cdfB[48] for search levels 0-1
    float bb  = Es + sw[0];
    float c16 = __shfl(bb, 4, 16)  * itot;      // cdfB[16]
    float c32 = __shfl(bb, 8, 16)  * itot;      // cdfB[32]
    float c48 = __shfl(bb, 12, 16) * itot;      // cdfB[48]

    // ---- z_edges ----
    float zp3 = updpp<0x111,true>(0.0f, zv[3]); // shfl_up 1 (sl0 masked)
    float ej0 = (sl == 0) ? (1.5f*zv[0] - 0.5f*zv[1]) : 0.5f*(zp3 + zv[0]);
    *(float4*)(edg + 4*sl) = make_float4(ej0, 0.5f*(zv[0]+zv[1]),
                                         0.5f*(zv[1]+zv[2]), 0.5f*(zv[2]+zv[3]));
    if (sl == 15) edg[64] = 1.5f*zv[3] - 0.5f*zv[2];
    // ---- stage coarse for sort ----
    *(float4*)(srt + 4*sl) = make_float4(zv[0], zv[1], zv[2], zv[3]);

    // ---- inverse-CDF fine sampling: 8 u's per lane ----
    // searchsorted(cdf65, u, 'right') = 1 + searchsorted_right(cdfB, u) since
    // cdf[0]=0 <= u always. lo in [0,64] after 7 steps; first 2 from registers.
    const float4 ua = ((const float4*)uu)[(size_t)ray*32 + 2*sl];
    const float4 ub = ((const float4*)uu)[(size_t)ray*32 + 2*sl + 1];
    const float uarr[8] = {ua.x,ua.y,ua.z,ua.w, ub.x,ub.y,ub.z,ub.w};
    float fz[8];
    #pragma unroll
    for (int t = 0; t < 8; ++t) {
        float u = uarr[t];
        // level 0: m=32 -> c32; level 1: m=48 or 16 -> registers
        bool d0 = (c32 <= u);
        int  lo = d0 ? 33 : 0;
        int  hi = d0 ? 64 : 32;
        float cm1 = d0 ? c48 : c16;
        int  m1 = (lo + hi) >> 1;               // 48 or 16
        bool d1 = (cm1 <= u);
        lo = d1 ? m1 + 1 : lo;
        hi = d1 ? hi : m1;
        #pragma unroll
        for (int it = 0; it < 5; ++it) {
            int m = (lo + hi) >> 1;
            bool c = cdfB[m] <= u;
            lo = c ? m+1 : lo;
            hi = c ? hi  : m;
        }
        int below = lo;                          // = clip(inds-1) in [0,64]
        int above = (lo < 64) ? lo + 1 : 64;     // = clip(inds)   in [1,64]
        int bm1   = (below > 0) ? below - 1 : 0;
        float c0 = cdfB[bm1];
        if (below == 0) c0 = 0.0f;               // cdf[0] = 0
        float c1 = cdfB[above - 1];
        float e0 = edg[below], e1 = edg[above];
        float dn = c1 - c0;
        if (dn < 1e-5f) dn = 1.0f;
        float tt = (u - c0) / dn;
        fz[t] = e0 + tt * (e1 - e0);
    }
    *(float4*)(srt + 64 + 8*sl)     = make_float4(fz[0],fz[1],fz[2],fz[3]);
    *(float4*)(srt + 64 + 8*sl + 4) = make_float4(fz[4],fz[5],fz[6],fz[7]);

    // ---- load sort layout: y[h] = element 16*sl + h (pads 192..255 = 1e30) ----
    float y[16];
    if (sl < 12) {
        #pragma unroll
        for (int tq = 0; tq < 4; ++tq) {
            float4 v = *(const float4*)(srt + 16*sl + 4*tq);
            y[4*tq+0]=v.x; y[4*tq+1]=v.y; y[4*tq+2]=v.z; y[4*tq+3]=v.w;
        }
    } else {
        #pragma unroll
        for (int h = 0; h < 16; ++h) y[h] = 1.0e30f;
    }

    // ---- bitonic sort of 256: all 36 substages with compile-time (K,J) ----
    substage<2,1>(y, sl);

    substage<4,2>(y, sl);   substage<4,1>(y, sl);

    substage<8,4>(y, sl);   substage<8,2>(y, sl);   substage<8,1>(y, sl);

    substage<16,8>(y, sl);  substage<16,4>(y, sl);  substage<16,2>(y, sl);
    substage<16,1>(y, sl);

    substage<32,16>(y, sl); substage<32,8>(y, sl);  substage<32,4>(y, sl);
    substage<32,2>(y, sl);  substage<32,1>(y, sl);

    substage<64,32>(y, sl); substage<64,16>(y, sl); substage<64,8>(y, sl);
    substage<64,4>(y, sl);  substage<64,2>(y, sl);  substage<64,1>(y, sl);

    substage<128,64>(y, sl); substage<128,32>(y, sl); substage<128,16>(y, sl);
    substage<128,8>(y, sl);  substage<128,4>(y, sl);  substage<128,2>(y, sl);
    substage<128,1>(y, sl);

    substage<256,128>(y, sl); substage<256,64>(y, sl); substage<256,32>(y, sl);
    substage<256,16>(y, sl);  substage<256,8>(y, sl);  substage<256,4>(y, sl);
    substage<256,2>(y, sl);   substage<256,1>(y, sl);

    // ---- write sorted to LDS ----
    if (sl < 12) {
        #pragma unroll
        for (int tq = 0; tq < 4; ++tq) {
            *(float4*)(srt + 16*sl + 4*tq) =
                make_float4(y[4*tq],y[4*tq+1],y[4*tq+2],y[4*tq+3]);
        }
    }

    // ---- z emit, coalesced: 48 float4 chunks/ray, lane sl takes chunk it*16+sl
    // (consecutive lanes -> consecutive 16B -> wave-contiguous NT stores) ----
    {
        float* zb = out_z + (size_t)ray * 192;
        #pragma unroll
        for (int it = 0; it < 3; ++it) {
            int c = it * 16 + sl;               // 0..47
            vf4 v = *(const vf4*)(srt + 4*c);   // 16B/lane, stride 16B: conflict-free
            __builtin_nontemporal_store(v, (vf4*)(zb + 4*c));
        }
    }

    // ---- emit points: per-ray group, 144 float4 chunks = 9 iterations ----
    float ox = org[(size_t)ray*3+0], oy = org[(size_t)ray*3+1], oz = org[(size_t)ray*3+2];
    float dx = dir[(size_t)ray*3+0], dy = dir[(size_t)ray*3+1], dz = dir[(size_t)ray*3+2];
    float* pbase = out_pts + (size_t)ray * 576;
    #pragma unroll
    for (int it = 0; it < 9; ++it) {
        int i  = it*16 + sl;                // chunk id 0..143, covers idx 4i..4i+3
        int q  = i / 3;
        int c0 = i - 3*q;                   // idx%3
        int k0 = i + q;                     // idx/3
        const float* zp = srt + k0;         // paired reads -> ds_read2_b32
        float z0 = zp[0];
        float z1 = zp[1];
        // m=0: ch=c0,z0    m=3: ch=c0,z1
        float o0  = (c0==0)?ox:((c0==1)?oy:oz);
        float dd0 = (c0==0)?dx:((c0==1)?dy:dz);
        float v0 = fmaf(dd0, z0, o0);
        float v3 = fmaf(dd0, z1, o0);
        // m=1: cm=c0+1 (wraps at 3 -> z1)
        int   c1i = (c0==2)?0:(c0+1);
        float zz1 = (c0==2)?z1:z0;
        float o1  = (c1i==0)?ox:((c1i==1)?oy:oz);
        float dd1 = (c1i==0)?dx:((c1i==1)?dy:dz);
        float v1 = fmaf(dd1, zz1, o1);
        // m=2: cm=c0+2 (wraps for c0>=1 -> z1)
        int   c2i = (c0==0)?2:(c0-1);
        float zz2 = (c0==0)?z0:z1;
        float o2  = (c2i==0)?ox:((c2i==1)?oy:oz);
        float dd2 = (c2i==0)?dx:((c2i==1)?dy:dz);
        float v2 = fmaf(dd2, zz2, o2);
        vf4 v = {v0, v1, v2, v3};
        __builtin_nontemporal_store(v, (vf4*)(pbase + 4*i));
    }
}

extern "C" void kernel_launch(void* const* d_in, const int* in_sizes, int n_in,
                              void* d_out, int out_size, void* d_ws, size_t ws_size,
                              hipStream_t stream) {
    const float* org   = (const float*)d_in[0];
    const float* dir   = (const float*)d_in[1];
    const float* dens  = (const float*)d_in[2];
    const float* trand = (const float*)d_in[3];
    const float* uv    = (const float*)d_in[4];
    int B = in_sizes[0] / 3;   // 131072

    float* out_pts = (float*)d_out;
    float* out_z   = out_pts + (size_t)B * 576;

    dim3 grid(B / RPB), block(128);
    hipLaunchKernelGGL(hier_sampler, grid, block, 0, stream,
                       org, dir, dens, trand, uv, out_pts, out_z);
}